// Round 1
// baseline (1360.202 us; speedup 1.0000x reference)
//
#include <hip/hip_runtime.h>
#include <math.h>

typedef _Float16 h8 __attribute__((ext_vector_type(8)));
typedef float f4 __attribute__((ext_vector_type(4)));

#define HASH_P1 2654435761u
#define HASH_P2 805459861u

// packed weight offsets (in halves) inside pack buffer
#define OFF_W0 0
#define OFF_W1 49152
#define OFF_W2 114688
#define OFF_W3 180224
#define OFF_W4 245760
#define OFF_D0 376832
#define OFF_D1 425984

struct ResArr { float r[24]; };

// ---------------------------------------------------------------------------
// Weight repack: fp32 [K][N] row-major  ->  f16 MFMA B-fragments.
// Fragment layout: frag f = ((kc*NT + nt)*64 + lane), element j (0..7):
//   B[k = kc*32 + (lane>>4)*8 + j][n = nt*16 + (lane&15)]
// so in the GEMM each lane does ONE contiguous 16B load per (kc, nt).
// ---------------------------------------------------------------------------
__global__ void lerf_pack(const float* __restrict__ w_in,
                          const float* __restrict__ w_h,
                          const float* __restrict__ w_out,
                          const float* __restrict__ dw_in,
                          const float* __restrict__ dw_out,
                          _Float16* __restrict__ pack) {
    int f = blockIdx.x * 256 + threadIdx.x;   // 65536 frags total
    const float* src; int K, N, base;
    if (f < 6144)       { src = w_in;          K = 192; N = 256; base = 0; }
    else if (f < 14336) { src = w_h;           K = 256; N = 256; base = 6144; }
    else if (f < 22528) { src = w_h + 65536;   K = 256; N = 256; base = 14336; }
    else if (f < 30720) { src = w_h + 131072;  K = 256; N = 256; base = 22528; }
    else if (f < 47104) { src = w_out;         K = 256; N = 512; base = 30720; }
    else if (f < 53248) { src = dw_in;         K = 192; N = 256; base = 47104; }
    else                { src = dw_out;        K = 256; N = 384; base = 53248; }
    (void)K;
    int fi   = f - base;
    int lane = fi & 63;
    int tile = fi >> 6;
    int NT   = N >> 4;
    int nt   = tile % NT;
    int kc   = tile / NT;
    int k0   = kc * 32 + (lane >> 4) * 8;
    int n    = nt * 16 + (lane & 15);
    h8 v;
#pragma unroll
    for (int j = 0; j < 8; ++j) v[j] = (_Float16)src[(size_t)(k0 + j) * N + n];
    *(h8*)(pack + (size_t)f * 8) = v;
}

// ---------------------------------------------------------------------------
// Hash encoding: scene contraction + trilinear hash lookup.
// RESTRUCTURED: one (point, level) pair per thread; level is WAVE-UNIFORM
// (gw % 24), point = lane within wave. 24x more waves than the one-thread-
// per-point version -> gather latency hidden by TLP instead of exposed.
// Writes x[N][192] as f16 (row-major), col = level*8 + feature.
// ---------------------------------------------------------------------------
__global__ void lerf_hash(const float* __restrict__ pos,
                          const float* __restrict__ t0,
                          const float* __restrict__ t1,
                          _Float16* __restrict__ xenc,
                          ResArr res, unsigned mask, int T, int N) {
    const int gw   = (blockIdx.x * 256 + threadIdx.x) >> 6;   // global wave id
    const int lane = threadIdx.x & 63;
    const int lvl  = gw % 24;                                 // wave-uniform level
    const size_t p = (size_t)(gw / 24) * 64 + (size_t)lane;   // point index
    if (p >= (size_t)N) return;

    float px = pos[p * 3 + 0];
    float py = pos[p * 3 + 1];
    float pz = pos[p * 3 + 2];
    float mag = sqrtf(px * px + py * py + pz * pz);
    if (mag >= 1.f) {
        float s = (2.f - 1.f / mag) / mag;
        px *= s; py *= s; pz *= s;
    }
    px = (px + 2.f) * 0.25f;
    py = (py + 2.f) * 0.25f;
    pz = (pz + 2.f) * 0.25f;

    // wave-uniform resolution select (unrolled cndmask chain; avoids
    // dynamic kernarg indexing -> scratch)
    float r = 0.f;
#pragma unroll
    for (int j = 0; j < 24; ++j) if (lvl == j) r = res.r[j];

    const float* tb = (lvl < 12) ? t0 : t1;
    const int    l  = (lvl < 12) ? lvl : lvl - 12;
    const float* tl = tb + (size_t)l * T * 8;

    float xs = px * r, ys = py * r, zs = pz * r;
    float fx = floorf(xs), fy = floorf(ys), fz = floorf(zs);
    float wx = xs - fx, wy = ys - fy, wz = zs - fz;
    unsigned ix = (unsigned)fx, iy = (unsigned)fy, iz = (unsigned)fz;
    unsigned hx0 = ix,              hx1 = ix + 1u;
    unsigned hy0 = iy * HASH_P1,    hy1 = (iy + 1u) * HASH_P1;
    unsigned hz0 = iz * HASH_P2,    hz1 = (iz + 1u) * HASH_P2;
    float a0=0.f,a1=0.f,a2=0.f,a3=0.f,a4=0.f,a5=0.f,a6=0.f,a7=0.f;
#pragma unroll
    for (int c = 0; c < 8; ++c) {
        unsigned h = ((c & 4) ? hx1 : hx0) ^ ((c & 2) ? hy1 : hy0) ^ ((c & 1) ? hz1 : hz0);
        unsigned idx = h & mask;
        const float4* fp = (const float4*)(tl + (size_t)idx * 8);
        float4 f0 = fp[0];
        float4 f1 = fp[1];
        float w = ((c & 4) ? wx : 1.f - wx) * ((c & 2) ? wy : 1.f - wy) * ((c & 1) ? wz : 1.f - wz);
        a0 += w * f0.x; a1 += w * f0.y; a2 += w * f0.z; a3 += w * f0.w;
        a4 += w * f1.x; a5 += w * f1.y; a6 += w * f1.z; a7 += w * f1.w;
    }
    h8 hv;
    hv[0]=(_Float16)a0; hv[1]=(_Float16)a1; hv[2]=(_Float16)a2; hv[3]=(_Float16)a3;
    hv[4]=(_Float16)a4; hv[5]=(_Float16)a5; hv[6]=(_Float16)a6; hv[7]=(_Float16)a7;
    *(h8*)(xenc + p * 192 + (size_t)lvl * 8) = hv;
}

// ---------------------------------------------------------------------------
// Fused MLP. Block = 64 rows, 256 threads (4 waves), waves split columns.
// A-frag: lane holds A[m=lane&15][k=(lane>>4)*8+j]   (ds_read_b128 from LDS)
// B-frag: lane holds B[k=(lane>>4)*8+j][n=lane&15]   (packed, 16B global load)
// C/D   : lane holds D[row=(lane>>4)*4+r][col=lane&15]
// ---------------------------------------------------------------------------
template<int NC>
__device__ __forceinline__ void zacc(f4 (&acc)[4][NC]) {
#pragma unroll
    for (int i = 0; i < 4; ++i)
#pragma unroll
        for (int j = 0; j < NC; ++j) acc[i][j] = (f4){0.f, 0.f, 0.f, 0.f};
}

template<int NC>
__device__ __forceinline__ void gemmN(const _Float16* in, int stride, int kch,
                                      const _Float16* wp, int NT, int nt0,
                                      int lane, f4 (&acc)[4][NC]) {
    const int m = lane & 15, q = lane >> 4;
    for (int kc = 0; kc < kch; ++kc) {
        h8 a[4];
#pragma unroll
        for (int rt = 0; rt < 4; ++rt)
            a[rt] = *(const h8*)(in + (rt * 16 + m) * stride + kc * 32 + q * 8);
#pragma unroll
        for (int ct = 0; ct < NC; ++ct) {
            h8 b = *(const h8*)(wp + ((size_t)((kc * NT + nt0 + ct) * 64 + lane)) * 8);
#pragma unroll
            for (int rt = 0; rt < 4; ++rt)
                acc[rt][ct] = __builtin_amdgcn_mfma_f32_16x16x32_f16(a[rt], b, acc[rt][ct], 0, 0, 0);
        }
    }
}

__device__ __forceinline__ void store_act(const f4 (&acc)[4][4], _Float16* outb,
                                          int stride, int lane) {
    const int m = lane & 15, q = lane >> 4;
#pragma unroll
    for (int rt = 0; rt < 4; ++rt)
#pragma unroll
        for (int ct = 0; ct < 4; ++ct)
#pragma unroll
            for (int r = 0; r < 4; ++r) {
                float v = fmaxf(acc[rt][ct][r], 0.f);
                outb[(rt * 16 + q * 4 + r) * stride + ct * 16 + m] = (_Float16)v;
            }
}

__global__ __launch_bounds__(256, 2)
void lerf_mlp(const _Float16* __restrict__ xenc, const _Float16* __restrict__ pack,
              float* __restrict__ out, int N) {
    __shared__ _Float16 bufU[64 * 264];
    __shared__ _Float16 bufV[64 * 264];
    __shared__ float rowsq[64];
    __shared__ float invn[64];
    const int tid  = threadIdx.x;
    const int lane = tid & 63, wave = tid >> 6;
    const int m = lane & 15, q = lane >> 4;
    const size_t row0 = (size_t)blockIdx.x * 64;

    if (tid < 64) rowsq[tid] = 0.f;
    // stage x tile (stride 200 halves; bank-shift 4 dwords/row)
#pragma unroll
    for (int it = 0; it < 6; ++it) {
        int c = tid + it * 256;
        int row = c / 24, col8 = c % 24;
        *(h8*)(bufU + row * 200 + col8 * 8) =
            *(const h8*)(xenc + (row0 + row) * 192 + (size_t)col8 * 8);
    }
    __syncthreads();

    f4 acc[4][4];

    // clip L0: 192->256, relu
    zacc(acc);
    gemmN<4>(bufU, 200, 6, pack + OFF_W0, 16, wave * 4, lane, acc);
    store_act(acc, bufV + wave * 64, 264, lane);
    __syncthreads();
    // clip L1
    zacc(acc);
    gemmN<4>(bufV, 264, 8, pack + OFF_W1, 16, wave * 4, lane, acc);
    store_act(acc, bufU + wave * 64, 264, lane);
    __syncthreads();
    // clip L2
    zacc(acc);
    gemmN<4>(bufU, 264, 8, pack + OFF_W2, 16, wave * 4, lane, acc);
    store_act(acc, bufV + wave * 64, 264, lane);
    __syncthreads();
    // clip L3  (h4 -> bufU)
    zacc(acc);
    gemmN<4>(bufV, 264, 8, pack + OFF_W3, 16, wave * 4, lane, acc);
    store_act(acc, bufU + wave * 64, 264, lane);
    __syncthreads();

    // clip out layer: 256->512, no relu, +1e-8, normalize. Two column passes.
    float s[4][4];
#pragma unroll
    for (int rt = 0; rt < 4; ++rt)
#pragma unroll
        for (int r = 0; r < 4; ++r) s[rt][r] = 0.f;

    // pass 1: cols 0..255 -> bufV
    zacc(acc);
    gemmN<4>(bufU, 264, 8, pack + OFF_W4, 32, wave * 4, lane, acc);
#pragma unroll
    for (int rt = 0; rt < 4; ++rt)
#pragma unroll
        for (int ct = 0; ct < 4; ++ct)
#pragma unroll
            for (int r = 0; r < 4; ++r) {
                float v = acc[rt][ct][r] + 1e-8f;
                s[rt][r] += v * v;
                (bufV + wave * 64)[(rt * 16 + q * 4 + r) * 264 + ct * 16 + m] = (_Float16)v;
            }
    // pass 2: cols 256..511 -> bufU (after all waves finish reading h4)
    zacc(acc);
    gemmN<4>(bufU, 264, 8, pack + OFF_W4, 32, 16 + wave * 4, lane, acc);
    __syncthreads();
#pragma unroll
    for (int rt = 0; rt < 4; ++rt)
#pragma unroll
        for (int ct = 0; ct < 4; ++ct)
#pragma unroll
            for (int r = 0; r < 4; ++r) {
                float v = acc[rt][ct][r] + 1e-8f;
                s[rt][r] += v * v;
                (bufU + wave * 64)[(rt * 16 + q * 4 + r) * 264 + ct * 16 + m] = (_Float16)v;
            }
    // per-row sum of squares: reduce over the 16 col-lanes, then across waves
#pragma unroll
    for (int rt = 0; rt < 4; ++rt)
#pragma unroll
        for (int r = 0; r < 4; ++r) {
            float t = s[rt][r];
            t += __shfl_xor(t, 1);
            t += __shfl_xor(t, 2);
            t += __shfl_xor(t, 4);
            t += __shfl_xor(t, 8);
            if (m == 0) atomicAdd(&rowsq[rt * 16 + q * 4 + r], t);
        }
    __syncthreads();
    if (tid < 64) invn[tid] = 1.f / fmaxf(sqrtf(rowsq[tid]), 1e-4f);
    __syncthreads();
    // write normalized clip (coalesced 1KB/instr)
    for (int it = 0; it < 128; ++it) {
        int flat = tid + it * 256;
        int row = flat >> 9, col = flat & 511;
        float v = (float)((col < 256) ? bufV[row * 264 + col] : bufU[row * 264 + (col - 256)]);
        out[(row0 + row) * 896 + col] = v * invn[row];
    }
    __syncthreads();

    // dino branch: reload x -> bufV
#pragma unroll
    for (int it = 0; it < 6; ++it) {
        int c = tid + it * 256;
        int row = c / 24, col8 = c % 24;
        *(h8*)(bufV + row * 200 + col8 * 8) =
            *(const h8*)(xenc + (row0 + row) * 192 + (size_t)col8 * 8);
    }
    __syncthreads();
    zacc(acc);
    gemmN<4>(bufV, 200, 6, pack + OFF_D0, 16, wave * 4, lane, acc);
    store_act(acc, bufU + wave * 64, 264, lane);   // relu(x @ dW_in)
    __syncthreads();
    f4 acc6[4][6];
    zacc(acc6);
    gemmN<6>(bufU, 264, 8, pack + OFF_D1, 24, wave * 6, lane, acc6);
#pragma unroll
    for (int rt = 0; rt < 4; ++rt)
#pragma unroll
        for (int ct = 0; ct < 6; ++ct)
#pragma unroll
            for (int r = 0; r < 4; ++r)
                out[(row0 + rt * 16 + q * 4 + r) * 896 + 512 + wave * 96 + ct * 16 + m] =
                    acc6[rt][ct][r];
}

// ---------------------------------------------------------------------------
extern "C" void kernel_launch(void* const* d_in, const int* in_sizes, int n_in,
                              void* d_out, int out_size, void* d_ws, size_t ws_size,
                              hipStream_t stream) {
    const float* positions = (const float*)d_in[0];
    const float* table0    = (const float*)d_in[1];
    const float* table1    = (const float*)d_in[2];
    const float* w_in      = (const float*)d_in[3];
    const float* w_h       = (const float*)d_in[4];
    const float* w_out     = (const float*)d_in[5];
    const float* dw_in     = (const float*)d_in[6];
    const float* dw_out    = (const float*)d_in[7];

    const int N = in_sizes[0] / 3;           // 131072
    const int T = in_sizes[1] / (12 * 8);    // 524288

    _Float16* xenc = (_Float16*)d_ws;                                   // N*192 halves
    _Float16* pack = (_Float16*)((char*)d_ws + (size_t)N * 192 * 2);    // 524288 halves

    // resolutions, replicating np: floor(start * exp((log(e)-log(s))/11)**i)
    // host glibc double math (closest available match to numpy's float64 path).
    ResArr ra;
    {
        double g0 = exp((log(128.0) - log(16.0)) / 11.0);
        for (int i = 0; i < 12; ++i) ra.r[i]      = (float)floor(16.0  * pow(g0, (double)i));
        double g1 = exp((log(512.0) - log(128.0)) / 11.0);
        for (int i = 0; i < 12; ++i) ra.r[12 + i] = (float)floor(128.0 * pow(g1, (double)i));
    }

    lerf_pack<<<dim3(256), dim3(256), 0, stream>>>(w_in, w_h, w_out, dw_in, dw_out, pack);
    // (N/64) point-groups x 24 levels, one wave each; 4 waves per block
    const int hash_waves  = (N / 64) * 24;
    const int hash_blocks = (hash_waves + 3) / 4;
    lerf_hash<<<dim3(hash_blocks), dim3(256), 0, stream>>>(
        positions, table0, table1, xenc, ra, (unsigned)(T - 1), T, N);
    lerf_mlp<<<dim3(N / 64), dim3(256), 0, stream>>>(xenc, pack, (float*)d_out, N);
}

// Round 2
// 1324.715 us; speedup vs baseline: 1.0268x; 1.0268x over previous
//
#include <hip/hip_runtime.h>
#include <math.h>

typedef _Float16 h8 __attribute__((ext_vector_type(8)));
typedef float f4 __attribute__((ext_vector_type(4)));

#define HASH_P1 2654435761u
#define HASH_P2 805459861u

// packed weight offsets (in halves) inside pack buffer
#define OFF_W0 0
#define OFF_W1 49152
#define OFF_W2 114688
#define OFF_W3 180224
#define OFF_W4 245760
#define OFF_D0 376832
#define OFF_D1 425984

struct ResArr { float r[24]; };

// ---------------------------------------------------------------------------
// Weight repack: fp32 [K][N] row-major  ->  f16 MFMA B-fragments.
// Fragment layout: frag f = ((kc*NT + nt)*64 + lane), element j (0..7):
//   B[k = kc*32 + (lane>>4)*8 + j][n = nt*16 + (lane&15)]
// so in the GEMM each lane does ONE contiguous 16B load per (kc, nt).
// ---------------------------------------------------------------------------
__global__ void lerf_pack(const float* __restrict__ w_in,
                          const float* __restrict__ w_h,
                          const float* __restrict__ w_out,
                          const float* __restrict__ dw_in,
                          const float* __restrict__ dw_out,
                          _Float16* __restrict__ pack) {
    int f = blockIdx.x * 256 + threadIdx.x;   // 65536 frags total
    const float* src; int K, N, base;
    if (f < 6144)       { src = w_in;          K = 192; N = 256; base = 0; }
    else if (f < 14336) { src = w_h;           K = 256; N = 256; base = 6144; }
    else if (f < 22528) { src = w_h + 65536;   K = 256; N = 256; base = 14336; }
    else if (f < 30720) { src = w_h + 131072;  K = 256; N = 256; base = 22528; }
    else if (f < 47104) { src = w_out;         K = 256; N = 512; base = 30720; }
    else if (f < 53248) { src = dw_in;         K = 192; N = 256; base = 47104; }
    else                { src = dw_out;        K = 256; N = 384; base = 53248; }
    (void)K;
    int fi   = f - base;
    int lane = fi & 63;
    int tile = fi >> 6;
    int NT   = N >> 4;
    int nt   = tile % NT;
    int kc   = tile / NT;
    int k0   = kc * 32 + (lane >> 4) * 8;
    int n    = nt * 16 + (lane & 15);
    h8 v;
#pragma unroll
    for (int j = 0; j < 8; ++j) v[j] = (_Float16)src[(size_t)(k0 + j) * N + n];
    *(h8*)(pack + (size_t)f * 8) = v;
}

// ---------------------------------------------------------------------------
// Hash encoding: scene contraction + trilinear hash lookup.
// One (point, level) pair per thread; level is WAVE-UNIFORM.
// LEVEL-MAJOR dispatch in groups of 4: waves are ordered so that only one
// 4-level group (<= 64 MB of tables) is resident at a time -> each fine
// level's 16 MB table stays L3-resident across its ~4 touches/line, and the
// 4 levels sharing a 64B xenc output line are written by adjacent waves
// (writes merge in L2).
// Writes x[N][192] as f16 (row-major), col = level*8 + feature.
// ---------------------------------------------------------------------------
__global__ void lerf_hash(const float* __restrict__ pos,
                          const float* __restrict__ t0,
                          const float* __restrict__ t1,
                          _Float16* __restrict__ xenc,
                          ResArr res, unsigned mask, int T, int N, int PG) {
    const int gw   = (blockIdx.x * 256 + threadIdx.x) >> 6;   // global wave id
    const int lane = threadIdx.x & 63;
    const int sub  = gw & 3;          // level within group-of-4
    const int pg   = gw >> 2;         // 0 .. 6*PG-1
    const int grp  = pg / PG;         // level group 0..5 (wave-uniform)
    const int pgi  = pg % PG;         // point group within level
    const int lvl  = grp * 4 + sub;   // wave-uniform level
    const size_t p = (size_t)pgi * 64 + (size_t)lane;         // point index
    if (lvl >= 24 || p >= (size_t)N) return;

    float px = pos[p * 3 + 0];
    float py = pos[p * 3 + 1];
    float pz = pos[p * 3 + 2];
    float mag = sqrtf(px * px + py * py + pz * pz);
    if (mag >= 1.f) {
        float s = (2.f - 1.f / mag) / mag;
        px *= s; py *= s; pz *= s;
    }
    px = (px + 2.f) * 0.25f;
    py = (py + 2.f) * 0.25f;
    pz = (pz + 2.f) * 0.25f;

    // wave-uniform resolution select (unrolled cndmask chain; avoids
    // dynamic kernarg indexing -> scratch)
    float r = 0.f;
#pragma unroll
    for (int j = 0; j < 24; ++j) if (lvl == j) r = res.r[j];

    const float* tb = (lvl < 12) ? t0 : t1;
    const int    l  = (lvl < 12) ? lvl : lvl - 12;
    const float* tl = tb + (size_t)l * T * 8;

    float xs = px * r, ys = py * r, zs = pz * r;
    float fx = floorf(xs), fy = floorf(ys), fz = floorf(zs);
    float wx = xs - fx, wy = ys - fy, wz = zs - fz;
    unsigned ix = (unsigned)fx, iy = (unsigned)fy, iz = (unsigned)fz;
    unsigned hx0 = ix,              hx1 = ix + 1u;
    unsigned hy0 = iy * HASH_P1,    hy1 = (iy + 1u) * HASH_P1;
    unsigned hz0 = iz * HASH_P2,    hz1 = (iz + 1u) * HASH_P2;
    float a0=0.f,a1=0.f,a2=0.f,a3=0.f,a4=0.f,a5=0.f,a6=0.f,a7=0.f;
#pragma unroll
    for (int c = 0; c < 8; ++c) {
        unsigned h = ((c & 4) ? hx1 : hx0) ^ ((c & 2) ? hy1 : hy0) ^ ((c & 1) ? hz1 : hz0);
        unsigned idx = h & mask;
        const float4* fp = (const float4*)(tl + (size_t)idx * 8);
        float4 f0 = fp[0];
        float4 f1 = fp[1];
        float w = ((c & 4) ? wx : 1.f - wx) * ((c & 2) ? wy : 1.f - wy) * ((c & 1) ? wz : 1.f - wz);
        a0 += w * f0.x; a1 += w * f0.y; a2 += w * f0.z; a3 += w * f0.w;
        a4 += w * f1.x; a5 += w * f1.y; a6 += w * f1.z; a7 += w * f1.w;
    }
    h8 hv;
    hv[0]=(_Float16)a0; hv[1]=(_Float16)a1; hv[2]=(_Float16)a2; hv[3]=(_Float16)a3;
    hv[4]=(_Float16)a4; hv[5]=(_Float16)a5; hv[6]=(_Float16)a6; hv[7]=(_Float16)a7;
    *(h8*)(xenc + p * 192 + (size_t)lvl * 8) = hv;
}

// ---------------------------------------------------------------------------
// Fused MLP. Block = 64 rows, 256 threads (4 waves), waves split columns.
// A-frag: lane holds A[m=lane&15][k=(lane>>4)*8+j]   (ds_read_b128 from LDS)
// B-frag: lane holds B[k=(lane>>4)*8+j][n=lane&15]   (packed, 16B global load)
// C/D   : lane holds D[row=(lane>>4)*4+r][col=lane&15]
// ---------------------------------------------------------------------------
template<int NC>
__device__ __forceinline__ void zacc(f4 (&acc)[4][NC]) {
#pragma unroll
    for (int i = 0; i < 4; ++i)
#pragma unroll
        for (int j = 0; j < NC; ++j) acc[i][j] = (f4){0.f, 0.f, 0.f, 0.f};
}

template<int NC>
__device__ __forceinline__ void gemmN(const _Float16* in, int stride, int kch,
                                      const _Float16* wp, int NT, int nt0,
                                      int lane, f4 (&acc)[4][NC]) {
    const int m = lane & 15, q = lane >> 4;
    for (int kc = 0; kc < kch; ++kc) {
        h8 a[4];
#pragma unroll
        for (int rt = 0; rt < 4; ++rt)
            a[rt] = *(const h8*)(in + (rt * 16 + m) * stride + kc * 32 + q * 8);
#pragma unroll
        for (int ct = 0; ct < NC; ++ct) {
            h8 b = *(const h8*)(wp + ((size_t)((kc * NT + nt0 + ct) * 64 + lane)) * 8);
#pragma unroll
            for (int rt = 0; rt < 4; ++rt)
                acc[rt][ct] = __builtin_amdgcn_mfma_f32_16x16x32_f16(a[rt], b, acc[rt][ct], 0, 0, 0);
        }
    }
}

__device__ __forceinline__ void store_act(const f4 (&acc)[4][4], _Float16* outb,
                                          int stride, int lane) {
    const int m = lane & 15, q = lane >> 4;
#pragma unroll
    for (int rt = 0; rt < 4; ++rt)
#pragma unroll
        for (int ct = 0; ct < 4; ++ct)
#pragma unroll
            for (int r = 0; r < 4; ++r) {
                float v = fmaxf(acc[rt][ct][r], 0.f);
                outb[(rt * 16 + q * 4 + r) * stride + ct * 16 + m] = (_Float16)v;
            }
}

__global__ __launch_bounds__(256, 2)
void lerf_mlp(const _Float16* __restrict__ xenc, const _Float16* __restrict__ pack,
              float* __restrict__ out, int N) {
    __shared__ _Float16 bufU[64 * 264];
    __shared__ _Float16 bufV[64 * 264];
    __shared__ float rowsq[64];
    __shared__ float invn[64];
    const int tid  = threadIdx.x;
    const int lane = tid & 63, wave = tid >> 6;
    const int m = lane & 15, q = lane >> 4;
    const size_t row0 = (size_t)blockIdx.x * 64;

    if (tid < 64) rowsq[tid] = 0.f;
    // stage x tile (stride 200 halves; bank-shift 4 dwords/row)
#pragma unroll
    for (int it = 0; it < 6; ++it) {
        int c = tid + it * 256;
        int row = c / 24, col8 = c % 24;
        *(h8*)(bufU + row * 200 + col8 * 8) =
            *(const h8*)(xenc + (row0 + row) * 192 + (size_t)col8 * 8);
    }
    __syncthreads();

    f4 acc[4][4];

    // clip L0: 192->256, relu
    zacc(acc);
    gemmN<4>(bufU, 200, 6, pack + OFF_W0, 16, wave * 4, lane, acc);
    store_act(acc, bufV + wave * 64, 264, lane);
    __syncthreads();
    // clip L1
    zacc(acc);
    gemmN<4>(bufV, 264, 8, pack + OFF_W1, 16, wave * 4, lane, acc);
    store_act(acc, bufU + wave * 64, 264, lane);
    __syncthreads();
    // clip L2
    zacc(acc);
    gemmN<4>(bufU, 264, 8, pack + OFF_W2, 16, wave * 4, lane, acc);
    store_act(acc, bufV + wave * 64, 264, lane);
    __syncthreads();
    // clip L3  (h4 -> bufU)
    zacc(acc);
    gemmN<4>(bufV, 264, 8, pack + OFF_W3, 16, wave * 4, lane, acc);
    store_act(acc, bufU + wave * 64, 264, lane);
    __syncthreads();

    // clip out layer: 256->512, no relu, +1e-8, normalize. Two column passes.
    float s[4][4];
#pragma unroll
    for (int rt = 0; rt < 4; ++rt)
#pragma unroll
        for (int r = 0; r < 4; ++r) s[rt][r] = 0.f;

    // pass 1: cols 0..255 -> bufV
    zacc(acc);
    gemmN<4>(bufU, 264, 8, pack + OFF_W4, 32, wave * 4, lane, acc);
#pragma unroll
    for (int rt = 0; rt < 4; ++rt)
#pragma unroll
        for (int ct = 0; ct < 4; ++ct)
#pragma unroll
            for (int r = 0; r < 4; ++r) {
                float v = acc[rt][ct][r] + 1e-8f;
                s[rt][r] += v * v;
                (bufV + wave * 64)[(rt * 16 + q * 4 + r) * 264 + ct * 16 + m] = (_Float16)v;
            }
    // pass 2: cols 256..511 -> bufU (after all waves finish reading h4)
    zacc(acc);
    gemmN<4>(bufU, 264, 8, pack + OFF_W4, 32, 16 + wave * 4, lane, acc);
    __syncthreads();
#pragma unroll
    for (int rt = 0; rt < 4; ++rt)
#pragma unroll
        for (int ct = 0; ct < 4; ++ct)
#pragma unroll
            for (int r = 0; r < 4; ++r) {
                float v = acc[rt][ct][r] + 1e-8f;
                s[rt][r] += v * v;
                (bufU + wave * 64)[(rt * 16 + q * 4 + r) * 264 + ct * 16 + m] = (_Float16)v;
            }
    // per-row sum of squares: reduce over the 16 col-lanes, then across waves
#pragma unroll
    for (int rt = 0; rt < 4; ++rt)
#pragma unroll
        for (int r = 0; r < 4; ++r) {
            float t = s[rt][r];
            t += __shfl_xor(t, 1);
            t += __shfl_xor(t, 2);
            t += __shfl_xor(t, 4);
            t += __shfl_xor(t, 8);
            if (m == 0) atomicAdd(&rowsq[rt * 16 + q * 4 + r], t);
        }
    __syncthreads();
    if (tid < 64) invn[tid] = 1.f / fmaxf(sqrtf(rowsq[tid]), 1e-4f);
    __syncthreads();
    // write normalized clip (coalesced 1KB/instr)
    for (int it = 0; it < 128; ++it) {
        int flat = tid + it * 256;
        int row = flat >> 9, col = flat & 511;
        float v = (float)((col < 256) ? bufV[row * 264 + col] : bufU[row * 264 + (col - 256)]);
        out[(row0 + row) * 896 + col] = v * invn[row];
    }
    __syncthreads();

    // dino branch: reload x -> bufV
#pragma unroll
    for (int it = 0; it < 6; ++it) {
        int c = tid + it * 256;
        int row = c / 24, col8 = c % 24;
        *(h8*)(bufV + row * 200 + col8 * 8) =
            *(const h8*)(xenc + (row0 + row) * 192 + (size_t)col8 * 8);
    }
    __syncthreads();
    zacc(acc);
    gemmN<4>(bufV, 200, 6, pack + OFF_D0, 16, wave * 4, lane, acc);
    store_act(acc, bufU + wave * 64, 264, lane);   // relu(x @ dW_in)
    __syncthreads();
    f4 acc6[4][6];
    zacc(acc6);
    gemmN<6>(bufU, 264, 8, pack + OFF_D1, 24, wave * 6, lane, acc6);
#pragma unroll
    for (int rt = 0; rt < 4; ++rt)
#pragma unroll
        for (int ct = 0; ct < 6; ++ct)
#pragma unroll
            for (int r = 0; r < 4; ++r)
                out[(row0 + rt * 16 + q * 4 + r) * 896 + 512 + wave * 96 + ct * 16 + m] =
                    acc6[rt][ct][r];
}

// ---------------------------------------------------------------------------
extern "C" void kernel_launch(void* const* d_in, const int* in_sizes, int n_in,
                              void* d_out, int out_size, void* d_ws, size_t ws_size,
                              hipStream_t stream) {
    const float* positions = (const float*)d_in[0];
    const float* table0    = (const float*)d_in[1];
    const float* table1    = (const float*)d_in[2];
    const float* w_in      = (const float*)d_in[3];
    const float* w_h       = (const float*)d_in[4];
    const float* w_out     = (const float*)d_in[5];
    const float* dw_in     = (const float*)d_in[6];
    const float* dw_out    = (const float*)d_in[7];

    const int N = in_sizes[0] / 3;           // 131072
    const int T = in_sizes[1] / (12 * 8);    // 524288

    _Float16* xenc = (_Float16*)d_ws;                                   // N*192 halves
    _Float16* pack = (_Float16*)((char*)d_ws + (size_t)N * 192 * 2);    // 524288 halves

    // resolutions, replicating np: floor(start * exp((log(e)-log(s))/11)**i)
    // host glibc double math (closest available match to numpy's float64 path).
    ResArr ra;
    {
        double g0 = exp((log(128.0) - log(16.0)) / 11.0);
        for (int i = 0; i < 12; ++i) ra.r[i]      = (float)floor(16.0  * pow(g0, (double)i));
        double g1 = exp((log(512.0) - log(128.0)) / 11.0);
        for (int i = 0; i < 12; ++i) ra.r[12 + i] = (float)floor(128.0 * pow(g1, (double)i));
    }

    lerf_pack<<<dim3(256), dim3(256), 0, stream>>>(w_in, w_h, w_out, dw_in, dw_out, pack);
    // level-major in groups of 4: 6 groups x PG point-waves x 4 levels
    const int PG          = (N + 63) / 64;         // point-groups (waves per level)
    const int hash_waves  = 6 * PG * 4;
    const int hash_blocks = (hash_waves + 3) / 4;
    lerf_hash<<<dim3(hash_blocks), dim3(256), 0, stream>>>(
        positions, table0, table1, xenc, ra, (unsigned)(T - 1), T, N, PG);
    lerf_mlp<<<dim3(N / 64), dim3(256), 0, stream>>>(xenc, pack, (float*)d_out, N);
}

// Round 3
// 1234.038 us; speedup vs baseline: 1.1022x; 1.0735x over previous
//
#include <hip/hip_runtime.h>
#include <math.h>

typedef _Float16 h8 __attribute__((ext_vector_type(8)));
typedef float f4 __attribute__((ext_vector_type(4)));

#define HASH_P1 2654435761u
#define HASH_P2 805459861u

// packed weight offsets (in halves) inside pack buffer
#define OFF_W0 0
#define OFF_W1 49152
#define OFF_W2 114688
#define OFF_W3 180224
#define OFF_W4 245760
#define OFF_D0 376832
#define OFF_D1 425984

struct ResArr { float r[24]; };

// ---------------------------------------------------------------------------
// Weight repack: fp32 [K][N] row-major  ->  f16 MFMA B-fragments.
// Fragment layout: frag f = ((kc*NT + nt)*64 + lane), element j (0..7):
//   B[k = kc*32 + (lane>>4)*8 + j][n = nt*16 + (lane&15)]
// so in the GEMM each lane does ONE contiguous 16B load per (kc, nt).
// ---------------------------------------------------------------------------
__global__ void lerf_pack(const float* __restrict__ w_in,
                          const float* __restrict__ w_h,
                          const float* __restrict__ w_out,
                          const float* __restrict__ dw_in,
                          const float* __restrict__ dw_out,
                          _Float16* __restrict__ pack) {
    int f = blockIdx.x * 256 + threadIdx.x;   // 65536 frags total
    const float* src; int K, N, base;
    if (f < 6144)       { src = w_in;          K = 192; N = 256; base = 0; }
    else if (f < 14336) { src = w_h;           K = 256; N = 256; base = 6144; }
    else if (f < 22528) { src = w_h + 65536;   K = 256; N = 256; base = 14336; }
    else if (f < 30720) { src = w_h + 131072;  K = 256; N = 256; base = 22528; }
    else if (f < 47104) { src = w_out;         K = 256; N = 512; base = 30720; }
    else if (f < 53248) { src = dw_in;         K = 192; N = 256; base = 47104; }
    else                { src = dw_out;        K = 256; N = 384; base = 53248; }
    (void)K;
    int fi   = f - base;
    int lane = fi & 63;
    int tile = fi >> 6;
    int NT   = N >> 4;
    int nt   = tile % NT;
    int kc   = tile / NT;
    int k0   = kc * 32 + (lane >> 4) * 8;
    int n    = nt * 16 + (lane & 15);
    h8 v;
#pragma unroll
    for (int j = 0; j < 8; ++j) v[j] = (_Float16)src[(size_t)(k0 + j) * N + n];
    *(h8*)(pack + (size_t)f * 8) = v;
}

// ---------------------------------------------------------------------------
// Hash encoding: scene contraction + trilinear hash lookup.
// XCD-AWARE LEVEL PARTITIONING: blocks round-robin across the 8 XCDs by
// blockIdx%8, so we give each XCD a disjoint set of 3 levels and have it
// walk them ONE AT A TIME (512 blocks x 256 points per level). The per-XCD
// instantaneous working set is a single 16 MB table against its private
// 4 MB L2 (random 4-touch reuse -> ~25% hit rate instead of ~6%), and only
// 8 tables (128 MB) are concurrently active device-wide (fits L3).
// Snake level->XCD map balances the ~15 "fully random" fine levels ~2/XCD:
//   slot0: lvl = 23-xcd   slot1: lvl = 8+xcd   slot2: lvl = 7-xcd
// Writes x[N][192] as f16 (row-major), col = level*8 + feature.
// ---------------------------------------------------------------------------
__global__ void lerf_hash(const float* __restrict__ pos,
                          const float* __restrict__ t0,
                          const float* __restrict__ t1,
                          _Float16* __restrict__ xenc,
                          ResArr res, unsigned mask, int T, int N) {
    const int b    = blockIdx.x;
    const int lane = threadIdx.x & 63;
    const int wave = threadIdx.x >> 6;
    const int xcd  = b & 7;
    const int s    = b >> 3;           // 0..1535 per XCD
    const int slot = s / 512;          // which of this XCD's 3 levels
    const int pb   = s % 512;          // point-block within level
    const int lvl  = (slot == 0) ? (23 - xcd) : ((slot == 1) ? (8 + xcd) : (7 - xcd));
    const size_t p = (size_t)pb * 256 + (size_t)wave * 64 + (size_t)lane;
    if (p >= (size_t)N) return;

    float px = pos[p * 3 + 0];
    float py = pos[p * 3 + 1];
    float pz = pos[p * 3 + 2];
    float mag = sqrtf(px * px + py * py + pz * pz);
    if (mag >= 1.f) {
        float sc = (2.f - 1.f / mag) / mag;
        px *= sc; py *= sc; pz *= sc;
    }
    px = (px + 2.f) * 0.25f;
    py = (py + 2.f) * 0.25f;
    pz = (pz + 2.f) * 0.25f;

    // wave-uniform resolution select (unrolled cndmask chain; avoids
    // dynamic kernarg indexing -> scratch)
    float r = 0.f;
#pragma unroll
    for (int j = 0; j < 24; ++j) if (lvl == j) r = res.r[j];

    const float* tb = (lvl < 12) ? t0 : t1;
    const int    l  = (lvl < 12) ? lvl : lvl - 12;
    const float* tl = tb + (size_t)l * T * 8;

    float xs = px * r, ys = py * r, zs = pz * r;
    float fx = floorf(xs), fy = floorf(ys), fz = floorf(zs);
    float wx = xs - fx, wy = ys - fy, wz = zs - fz;
    unsigned ix = (unsigned)fx, iy = (unsigned)fy, iz = (unsigned)fz;
    unsigned hx0 = ix,              hx1 = ix + 1u;
    unsigned hy0 = iy * HASH_P1,    hy1 = (iy + 1u) * HASH_P1;
    unsigned hz0 = iz * HASH_P2,    hz1 = (iz + 1u) * HASH_P2;
    float a0=0.f,a1=0.f,a2=0.f,a3=0.f,a4=0.f,a5=0.f,a6=0.f,a7=0.f;
#pragma unroll
    for (int c = 0; c < 8; ++c) {
        unsigned h = ((c & 4) ? hx1 : hx0) ^ ((c & 2) ? hy1 : hy0) ^ ((c & 1) ? hz1 : hz0);
        unsigned idx = h & mask;
        const float4* fp = (const float4*)(tl + (size_t)idx * 8);
        float4 f0 = fp[0];
        float4 f1 = fp[1];
        float w = ((c & 4) ? wx : 1.f - wx) * ((c & 2) ? wy : 1.f - wy) * ((c & 1) ? wz : 1.f - wz);
        a0 += w * f0.x; a1 += w * f0.y; a2 += w * f0.z; a3 += w * f0.w;
        a4 += w * f1.x; a5 += w * f1.y; a6 += w * f1.z; a7 += w * f1.w;
    }
    h8 hv;
    hv[0]=(_Float16)a0; hv[1]=(_Float16)a1; hv[2]=(_Float16)a2; hv[3]=(_Float16)a3;
    hv[4]=(_Float16)a4; hv[5]=(_Float16)a5; hv[6]=(_Float16)a6; hv[7]=(_Float16)a7;
    *(h8*)(xenc + p * 192 + (size_t)lvl * 8) = hv;
}

// ---------------------------------------------------------------------------
// Fused MLP. Block = 64 rows, 256 threads (4 waves), waves split columns.
// A-frag: lane holds A[m=lane&15][k=(lane>>4)*8+j]   (ds_read_b128 from LDS)
// B-frag: lane holds B[k=(lane>>4)*8+j][n=lane&15]   (packed, 16B global load)
// C/D   : lane holds D[row=(lane>>4)*4+r][col=lane&15]
// ---------------------------------------------------------------------------
template<int NC>
__device__ __forceinline__ void zacc(f4 (&acc)[4][NC]) {
#pragma unroll
    for (int i = 0; i < 4; ++i)
#pragma unroll
        for (int j = 0; j < NC; ++j) acc[i][j] = (f4){0.f, 0.f, 0.f, 0.f};
}

template<int NC>
__device__ __forceinline__ void gemmN(const _Float16* in, int stride, int kch,
                                      const _Float16* wp, int NT, int nt0,
                                      int lane, f4 (&acc)[4][NC]) {
    const int m = lane & 15, q = lane >> 4;
    for (int kc = 0; kc < kch; ++kc) {
        h8 a[4];
#pragma unroll
        for (int rt = 0; rt < 4; ++rt)
            a[rt] = *(const h8*)(in + (rt * 16 + m) * stride + kc * 32 + q * 8);
#pragma unroll
        for (int ct = 0; ct < NC; ++ct) {
            h8 b = *(const h8*)(wp + ((size_t)((kc * NT + nt0 + ct) * 64 + lane)) * 8);
#pragma unroll
            for (int rt = 0; rt < 4; ++rt)
                acc[rt][ct] = __builtin_amdgcn_mfma_f32_16x16x32_f16(a[rt], b, acc[rt][ct], 0, 0, 0);
        }
    }
}

__device__ __forceinline__ void store_act(const f4 (&acc)[4][4], _Float16* outb,
                                          int stride, int lane) {
    const int m = lane & 15, q = lane >> 4;
#pragma unroll
    for (int rt = 0; rt < 4; ++rt)
#pragma unroll
        for (int ct = 0; ct < 4; ++ct)
#pragma unroll
            for (int r = 0; r < 4; ++r) {
                float v = fmaxf(acc[rt][ct][r], 0.f);
                outb[(rt * 16 + q * 4 + r) * stride + ct * 16 + m] = (_Float16)v;
            }
}

__global__ __launch_bounds__(256, 2)
void lerf_mlp(const _Float16* __restrict__ xenc, const _Float16* __restrict__ pack,
              float* __restrict__ out, int N) {
    __shared__ _Float16 bufU[64 * 264];
    __shared__ _Float16 bufV[64 * 264];
    __shared__ float rowsq[64];
    __shared__ float invn[64];
    const int tid  = threadIdx.x;
    const int lane = tid & 63, wave = tid >> 6;
    const int m = lane & 15, q = lane >> 4;
    const size_t row0 = (size_t)blockIdx.x * 64;

    if (tid < 64) rowsq[tid] = 0.f;
    // stage x tile (stride 200 halves; bank-shift 4 dwords/row)
#pragma unroll
    for (int it = 0; it < 6; ++it) {
        int c = tid + it * 256;
        int row = c / 24, col8 = c % 24;
        *(h8*)(bufU + row * 200 + col8 * 8) =
            *(const h8*)(xenc + (row0 + row) * 192 + (size_t)col8 * 8);
    }
    __syncthreads();

    f4 acc[4][4];

    // clip L0: 192->256, relu
    zacc(acc);
    gemmN<4>(bufU, 200, 6, pack + OFF_W0, 16, wave * 4, lane, acc);
    store_act(acc, bufV + wave * 64, 264, lane);
    __syncthreads();
    // clip L1
    zacc(acc);
    gemmN<4>(bufV, 264, 8, pack + OFF_W1, 16, wave * 4, lane, acc);
    store_act(acc, bufU + wave * 64, 264, lane);
    __syncthreads();
    // clip L2
    zacc(acc);
    gemmN<4>(bufU, 264, 8, pack + OFF_W2, 16, wave * 4, lane, acc);
    store_act(acc, bufV + wave * 64, 264, lane);
    __syncthreads();
    // clip L3  (h4 -> bufU)
    zacc(acc);
    gemmN<4>(bufV, 264, 8, pack + OFF_W3, 16, wave * 4, lane, acc);
    store_act(acc, bufU + wave * 64, 264, lane);
    __syncthreads();

    // clip out layer: 256->512, no relu, +1e-8, normalize. Two column passes.
    float s[4][4];
#pragma unroll
    for (int rt = 0; rt < 4; ++rt)
#pragma unroll
        for (int r = 0; r < 4; ++r) s[rt][r] = 0.f;

    // pass 1: cols 0..255 -> bufV
    zacc(acc);
    gemmN<4>(bufU, 264, 8, pack + OFF_W4, 32, wave * 4, lane, acc);
#pragma unroll
    for (int rt = 0; rt < 4; ++rt)
#pragma unroll
        for (int ct = 0; ct < 4; ++ct)
#pragma unroll
            for (int r = 0; r < 4; ++r) {
                float v = acc[rt][ct][r] + 1e-8f;
                s[rt][r] += v * v;
                (bufV + wave * 64)[(rt * 16 + q * 4 + r) * 264 + ct * 16 + m] = (_Float16)v;
            }
    // pass 2: cols 256..511 -> bufU (after all waves finish reading h4)
    zacc(acc);
    gemmN<4>(bufU, 264, 8, pack + OFF_W4, 32, 16 + wave * 4, lane, acc);
    __syncthreads();
#pragma unroll
    for (int rt = 0; rt < 4; ++rt)
#pragma unroll
        for (int ct = 0; ct < 4; ++ct)
#pragma unroll
            for (int r = 0; r < 4; ++r) {
                float v = acc[rt][ct][r] + 1e-8f;
                s[rt][r] += v * v;
                (bufU + wave * 64)[(rt * 16 + q * 4 + r) * 264 + ct * 16 + m] = (_Float16)v;
            }
    // per-row sum of squares: reduce over the 16 col-lanes, then across waves
#pragma unroll
    for (int rt = 0; rt < 4; ++rt)
#pragma unroll
        for (int r = 0; r < 4; ++r) {
            float t = s[rt][r];
            t += __shfl_xor(t, 1);
            t += __shfl_xor(t, 2);
            t += __shfl_xor(t, 4);
            t += __shfl_xor(t, 8);
            if (m == 0) atomicAdd(&rowsq[rt * 16 + q * 4 + r], t);
        }
    __syncthreads();
    if (tid < 64) invn[tid] = 1.f / fmaxf(sqrtf(rowsq[tid]), 1e-4f);
    __syncthreads();
    // write normalized clip (coalesced 1KB/instr)
    for (int it = 0; it < 128; ++it) {
        int flat = tid + it * 256;
        int row = flat >> 9, col = flat & 511;
        float v = (float)((col < 256) ? bufV[row * 264 + col] : bufU[row * 264 + (col - 256)]);
        out[(row0 + row) * 896 + col] = v * invn[row];
    }
    __syncthreads();

    // dino branch: reload x -> bufV
#pragma unroll
    for (int it = 0; it < 6; ++it) {
        int c = tid + it * 256;
        int row = c / 24, col8 = c % 24;
        *(h8*)(bufV + row * 200 + col8 * 8) =
            *(const h8*)(xenc + (row0 + row) * 192 + (size_t)col8 * 8);
    }
    __syncthreads();
    zacc(acc);
    gemmN<4>(bufV, 200, 6, pack + OFF_D0, 16, wave * 4, lane, acc);
    store_act(acc, bufU + wave * 64, 264, lane);   // relu(x @ dW_in)
    __syncthreads();
    f4 acc6[4][6];
    zacc(acc6);
    gemmN<6>(bufU, 264, 8, pack + OFF_D1, 24, wave * 6, lane, acc6);
#pragma unroll
    for (int rt = 0; rt < 4; ++rt)
#pragma unroll
        for (int ct = 0; ct < 6; ++ct)
#pragma unroll
            for (int r = 0; r < 4; ++r)
                out[(row0 + rt * 16 + q * 4 + r) * 896 + 512 + wave * 96 + ct * 16 + m] =
                    acc6[rt][ct][r];
}

// ---------------------------------------------------------------------------
extern "C" void kernel_launch(void* const* d_in, const int* in_sizes, int n_in,
                              void* d_out, int out_size, void* d_ws, size_t ws_size,
                              hipStream_t stream) {
    const float* positions = (const float*)d_in[0];
    const float* table0    = (const float*)d_in[1];
    const float* table1    = (const float*)d_in[2];
    const float* w_in      = (const float*)d_in[3];
    const float* w_h       = (const float*)d_in[4];
    const float* w_out     = (const float*)d_in[5];
    const float* dw_in     = (const float*)d_in[6];
    const float* dw_out    = (const float*)d_in[7];

    const int N = in_sizes[0] / 3;           // 131072
    const int T = in_sizes[1] / (12 * 8);    // 524288

    _Float16* xenc = (_Float16*)d_ws;                                   // N*192 halves
    _Float16* pack = (_Float16*)((char*)d_ws + (size_t)N * 192 * 2);    // 524288 halves

    // resolutions, replicating np: floor(start * exp((log(e)-log(s))/11)**i)
    // host glibc double math (closest available match to numpy's float64 path).
    ResArr ra;
    {
        double g0 = exp((log(128.0) - log(16.0)) / 11.0);
        for (int i = 0; i < 12; ++i) ra.r[i]      = (float)floor(16.0  * pow(g0, (double)i));
        double g1 = exp((log(512.0) - log(128.0)) / 11.0);
        for (int i = 0; i < 12; ++i) ra.r[12 + i] = (float)floor(128.0 * pow(g1, (double)i));
    }

    lerf_pack<<<dim3(256), dim3(256), 0, stream>>>(w_in, w_h, w_out, dw_in, dw_out, pack);
    // XCD-partitioned: 8 XCDs x 3 levels x 512 point-blocks (256 pts each)
    const int hash_blocks = 8 * 3 * 512;     // 12288, covers N=131072 exactly
    lerf_hash<<<dim3(hash_blocks), dim3(256), 0, stream>>>(
        positions, table0, table1, xenc, ra, (unsigned)(T - 1), T, N);
    lerf_mlp<<<dim3(N / 64), dim3(256), 0, stream>>>(xenc, pack, (float*)d_out, N);
}